// Round 4
// baseline (134.773 us; speedup 1.0000x reference)
//
#include <hip/hip_runtime.h>
#include <math.h>

// Problem constants (match reference)
#define Kp 128
#define Tn 64
#define Dn 128
#define Hn 512
#define ETS 68   // floats per transposed row (64 data + 4 pad); 68%32=4 -> row-start banks cycle

// Swizzled transposed-embedding index for element (d, i):
// column granules of 4 rotated by d/4 -> breaks the 16-way transpose-write
// bank conflict while keeping 4-float contiguity for f4 reads.
__device__ __forceinline__ int etIdx(int d, int i) {
    return d * ETS + (((((i >> 2) + (d >> 2)) & 15) << 2) | (i & 3));
}

__global__ __launch_bounds__(512, 1) void ep_kernel(
    const int*   __restrict__ Nptr,    // [1]
    const int*   __restrict__ leaf,    // K x 64 (int32)
    const float* __restrict__ emb,     // K x 64 x 128
    const float* __restrict__ W1,      // 256 x 512
    const float* __restrict__ b1,      // 512
    const float* __restrict__ W2,      // 512 x 128
    const float* __restrict__ b2,      // 128
    const float* __restrict__ gum,     // K x 4096
    const float* __restrict__ u1,      // K
    const float* __restrict__ u2,      // K
    float* __restrict__ out)           // 17152 floats
{
    const int k    = blockIdx.x;
    const int tid  = threadIdx.x;
    const int lane = tid & 63;
    const int wid  = tid >> 6;

    __shared__ float ET[Dn * ETS];     // 34816 B
    __shared__ float scratch[6016];    // Gram partials (120*48 + 16*16), reused by MLP partials
    __shared__ float xs[256];
    __shared__ float hsh[Hn];
    __shared__ float nI[Tn];
    __shared__ float embs[Dn];
    __shared__ float sBest[8]; __shared__ int sIdx[8]; __shared__ float sW[8]; __shared__ float sSum[8];
    __shared__ float sD1[2]; __shared__ float sD2[2];
    __shared__ int   sOnes;
    __shared__ int   fIdx; __shared__ float fW; __shared__ float fS;

    // --- role decode: 480 upper-tile slots (tile u, d-quarter q) + 32 diag slots ---
    const bool isUp = tid < 480;
    int ty = 0, tx = 0, tq = 0, uu = 0, dt = 0, dh = 0;
    if (isUp) {
        uu = tid >> 2; tq = tid & 3;
        while (uu >= 15 * (ty + 1) - ((ty + 1) * ty) / 2) ++ty;   // triangular decode, ty<tx
        tx = ty + 1 + (uu - (15 * ty - (ty * (ty - 1)) / 2));
    } else {
        int w = tid - 480; dt = w >> 1; dh = w & 1;
    }
    const bool ownU = isUp && (tq == 0);
    const bool ownD = (!isUp) && (dh == 0);

    // --- ones count (wave 0) ---
    if (tid < 64) {
        unsigned long long m = __ballot(leaf[k * Tn + tid] == 1);
        if (tid == 0) sOnes = __popcll(m);
    }

    // --- EARLY global loads: embeddings + owner gumbel tiles (latency hidden by transpose/Gram) ---
    float4 ev[4];
    {
        const float4* src = (const float4*)(emb + (size_t)k * Tn * Dn);
        #pragma unroll
        for (int it = 0; it < 4; ++it) ev[it] = src[tid + it * 512];
    }
    float4 gA[4] = {}, gB[4] = {};
    {
        const float* gk = gum + (size_t)k * (Tn * Tn);
        if (ownU) {
            #pragma unroll
            for (int r = 0; r < 4; ++r) {
                gA[r] = *(const float4*)&gk[(4 * ty + r) * Tn + 4 * tx];  // tile (ty,tx)
                gB[r] = *(const float4*)&gk[(4 * tx + r) * Tn + 4 * ty];  // mirrored tile (tx,ty)
            }
        } else if (ownD) {
            #pragma unroll
            for (int r = 0; r < 4; ++r) gA[r] = *(const float4*)&gk[(4 * dt + r) * Tn + 4 * dt];
        }
    }

    // --- transpose embeddings into swizzled LDS ---
    #pragma unroll
    for (int it = 0; it < 4; ++it) {
        int f4 = tid + it * 512;
        int i  = f4 >> 5;            // subtree index (32 f4 per row of 128 dims)
        int d0 = (f4 & 31) << 2;     // starting dim
        ET[etIdx(d0 + 0, i)] = ev[it].x;
        ET[etIdx(d0 + 1, i)] = ev[it].y;
        ET[etIdx(d0 + 2, i)] = ev[it].z;
        ET[etIdx(d0 + 3, i)] = ev[it].w;
    }
    __syncthreads();

    // --- symmetric-folded Gram: upper tiles split 4-way over d (interleaved d=q+4m
    //     so co-tile lanes hit disjoint bank quads); diag tiles split 2-way ---
    float4 ac0 = {0,0,0,0}, ac1 = {0,0,0,0}, ac2 = {0,0,0,0}, ac3 = {0,0,0,0};
    if (isUp) {
        const int ra = 4 * ty, rb = 4 * tx;
        #pragma unroll 4
        for (int m = 0; m < 32; ++m) {
            int d = tq + 4 * m;
            float4 a = *(const float4*)&ET[etIdx(d, ra)];
            float4 b = *(const float4*)&ET[etIdx(d, rb)];
            ac0.x += a.x * b.x; ac0.y += a.x * b.y; ac0.z += a.x * b.z; ac0.w += a.x * b.w;
            ac1.x += a.y * b.x; ac1.y += a.y * b.y; ac1.z += a.y * b.z; ac1.w += a.y * b.w;
            ac2.x += a.z * b.x; ac2.y += a.z * b.y; ac2.z += a.z * b.z; ac2.w += a.z * b.w;
            ac3.x += a.w * b.x; ac3.y += a.w * b.y; ac3.z += a.w * b.z; ac3.w += a.w * b.w;
        }
        if (tq > 0) {
            float* s = &scratch[uu * 48 + (tq - 1) * 16];
            *(float4*)&s[0] = ac0; *(float4*)&s[4]  = ac1;
            *(float4*)&s[8] = ac2; *(float4*)&s[12] = ac3;
        }
    } else {
        const int ra = 4 * dt;
        #pragma unroll 4
        for (int m = 0; m < 64; ++m) {
            int d = dh + 2 * m;
            float4 a = *(const float4*)&ET[etIdx(d, ra)];
            ac0.x += a.x * a.x; ac0.y += a.x * a.y; ac0.z += a.x * a.z; ac0.w += a.x * a.w;
            ac1.x += a.y * a.x; ac1.y += a.y * a.y; ac1.z += a.y * a.z; ac1.w += a.y * a.w;
            ac2.x += a.z * a.x; ac2.y += a.z * a.y; ac2.z += a.z * a.z; ac2.w += a.z * a.w;
            ac3.x += a.w * a.x; ac3.y += a.w * a.y; ac3.z += a.w * a.z; ac3.w += a.w * a.w;
        }
        if (dh == 1) {
            float* s = &scratch[5760 + dt * 16];
            *(float4*)&s[0] = ac0; *(float4*)&s[4]  = ac1;
            *(float4*)&s[8] = ac2; *(float4*)&s[12] = ac3;
        }
    }
    __syncthreads();

    // --- owners combine partials; diag owners publish norms ---
    if (ownU) {
        #pragma unroll
        for (int p = 0; p < 3; ++p) {
            const float* s = &scratch[uu * 48 + p * 16];
            float4 t0 = *(const float4*)&s[0], t1 = *(const float4*)&s[4];
            float4 t2 = *(const float4*)&s[8], t3 = *(const float4*)&s[12];
            ac0.x += t0.x; ac0.y += t0.y; ac0.z += t0.z; ac0.w += t0.w;
            ac1.x += t1.x; ac1.y += t1.y; ac1.z += t1.z; ac1.w += t1.w;
            ac2.x += t2.x; ac2.y += t2.y; ac2.z += t2.z; ac2.w += t2.w;
            ac3.x += t3.x; ac3.y += t3.y; ac3.z += t3.z; ac3.w += t3.w;
        }
    } else if (ownD) {
        const float* s = &scratch[5760 + dt * 16];
        float4 t0 = *(const float4*)&s[0], t1 = *(const float4*)&s[4];
        float4 t2 = *(const float4*)&s[8], t3 = *(const float4*)&s[12];
        ac0.x += t0.x; ac0.y += t0.y; ac0.z += t0.z; ac0.w += t0.w;
        ac1.x += t1.x; ac1.y += t1.y; ac1.z += t1.z; ac1.w += t1.w;
        ac2.x += t2.x; ac2.y += t2.y; ac2.z += t2.z; ac2.w += t2.w;
        ac3.x += t3.x; ac3.y += t3.y; ac3.z += t3.z; ac3.w += t3.w;
        nI[4 * dt + 0] = ac0.x; nI[4 * dt + 1] = ac1.y;
        nI[4 * dt + 2] = ac2.z; nI[4 * dt + 3] = ac3.w;
    }
    __syncthreads();   // nI visible to all owners

    // --- w + argmax(w+g) over both tile orientations + direct expsum ---
    float es = 0.0f, best = -INFINITY, bestW = 0.0f;
    int   bestIdx = 0;
    {
        float accf[16];
        *(float4*)&accf[0] = ac0; *(float4*)&accf[4]  = ac1;
        *(float4*)&accf[8] = ac2; *(float4*)&accf[12] = ac3;
        float gAf[16], gBf[16];
        *(float4*)&gAf[0] = gA[0]; *(float4*)&gAf[4]  = gA[1];
        *(float4*)&gAf[8] = gA[2]; *(float4*)&gAf[12] = gA[3];
        *(float4*)&gBf[0] = gB[0]; *(float4*)&gBf[4]  = gB[1];
        *(float4*)&gBf[8] = gB[2]; *(float4*)&gBf[12] = gB[3];
        if (ownU) {
            float ni[4], nj[4];
            #pragma unroll
            for (int r = 0; r < 4; ++r) { ni[r] = nI[4 * ty + r]; nj[r] = nI[4 * tx + r]; }
            #pragma unroll
            for (int r = 0; r < 4; ++r) {
                #pragma unroll
                for (int c = 0; c < 4; ++c) {
                    float pd2 = ni[r] + nj[c] - 2.0f * accf[r * 4 + c];
                    float wv  = -sqrtf(fmaxf(pd2, 0.0f) + 1e-12f);
                    es += 2.0f * expf(wv);                      // covers (i,j) and (j,i)
                    int i = 4 * ty + r, j = 4 * tx + c;
                    float wg1 = wv + gAf[r * 4 + c]; int id1 = i * Tn + j;
                    if (wg1 > best || (wg1 == best && id1 < bestIdx)) { best = wg1; bestIdx = id1; bestW = wv; }
                    float wg2 = wv + gBf[c * 4 + r]; int id2 = j * Tn + i;
                    if (wg2 > best || (wg2 == best && id2 < bestIdx)) { best = wg2; bestIdx = id2; bestW = wv; }
                }
            }
        } else if (ownD) {
            float ni[4];
            #pragma unroll
            for (int r = 0; r < 4; ++r) ni[r] = nI[4 * dt + r];
            #pragma unroll
            for (int r = 0; r < 4; ++r) {
                #pragma unroll
                for (int c = 0; c < 4; ++c) {
                    if (c > r) {
                        float pd2 = ni[r] + ni[c] - 2.0f * accf[r * 4 + c];
                        float wv  = -sqrtf(fmaxf(pd2, 0.0f) + 1e-12f);
                        es += 2.0f * expf(wv);
                        int i = 4 * dt + r, j = 4 * dt + c;
                        float wg1 = wv + gAf[r * 4 + c]; int id1 = i * Tn + j;
                        if (wg1 > best || (wg1 == best && id1 < bestIdx)) { best = wg1; bestIdx = id1; bestW = wv; }
                        float wg2 = wv + gAf[c * 4 + r]; int id2 = j * Tn + i;
                        if (wg2 > best || (wg2 == best && id2 < bestIdx)) { best = wg2; bestIdx = id2; bestW = wv; }
                    }
                }
            }
        }
    }

    // --- fused block reduction (8 waves): argmax triple + expsum ---
    #pragma unroll
    for (int off = 32; off > 0; off >>= 1) {
        float ob = __shfl_down(best, off);
        int   oi = __shfl_down(bestIdx, off);
        float ow = __shfl_down(bestW, off);
        float oe = __shfl_down(es, off);
        if (ob > best || (ob == best && oi < bestIdx)) { best = ob; bestIdx = oi; bestW = ow; }
        es += oe;
    }
    if (lane == 0) { sBest[wid] = best; sIdx[wid] = bestIdx; sW[wid] = bestW; sSum[wid] = es; }
    __syncthreads();
    if (tid == 0) {
        best = sBest[0]; bestIdx = sIdx[0]; bestW = sW[0];
        float essum = sSum[0];
        #pragma unroll
        for (int q = 1; q < 8; ++q) {
            if (sBest[q] > best || (sBest[q] == best && sIdx[q] < bestIdx)) {
                best = sBest[q]; bestIdx = sIdx[q]; bestW = sW[q];
            }
            essum += sSum[q];
        }
        fIdx = bestIdx; fW = bestW; fS = essum;
    }
    __syncthreads();

    const int i1 = fIdx >> 6;
    const int i2 = fIdx & 63;

    // --- gather children into xs = concat(c1, c2) ---
    if (tid < 256) xs[tid] = (tid < 128) ? ET[etIdx(tid, i1)] : ET[etIdx(tid - 128, i2)];
    __syncthreads();

    // --- MLP layer 1: 4-way i-split, thread owns 4 cols; padded-stride partials ---
    {
        const int j0 = 4 * (tid & 127);
        const int ih = tid >> 7;
        const float* W1r = W1 + j0;
        float4 a = {0,0,0,0};
        const int ib = ih * 64;
        #pragma unroll 4
        for (int i = ib; i < ib + 64; i += 4) {
            float4 x  = *(const float4*)&xs[i];
            float4 w0 = *(const float4*)&W1r[(size_t)(i + 0) * Hn];
            float4 w1 = *(const float4*)&W1r[(size_t)(i + 1) * Hn];
            float4 w2 = *(const float4*)&W1r[(size_t)(i + 2) * Hn];
            float4 w3 = *(const float4*)&W1r[(size_t)(i + 3) * Hn];
            a.x += x.x * w0.x + x.y * w1.x + x.z * w2.x + x.w * w3.x;
            a.y += x.x * w0.y + x.y * w1.y + x.z * w2.y + x.w * w3.y;
            a.z += x.x * w0.z + x.y * w1.z + x.z * w2.z + x.w * w3.z;
            a.w += x.x * w0.w + x.y * w1.w + x.z * w2.w + x.w * w3.w;
        }
        *(float4*)&scratch[ih * 516 + j0] = a;   // stride 516: 516%32=4 -> conflict-free combine
    }
    __syncthreads();
    hsh[tid] = fmaxf(b1[tid] + scratch[tid] + scratch[516 + tid]
                              + scratch[1032 + tid] + scratch[1548 + tid], 0.0f);
    __syncthreads();

    // --- MLP layer 2: 16-way j-split, thread owns 4 output cols ---
    {
        const int jh  = tid >> 5;
        const int dd4 = 4 * (tid & 31);
        float4 a = {0,0,0,0};
        const int jb = jh * 32;
        #pragma unroll 4
        for (int j = jb; j < jb + 32; j += 4) {
            float4 h4 = *(const float4*)&hsh[j];
            float4 w0 = *(const float4*)&W2[(size_t)(j + 0) * Dn + dd4];
            float4 w1 = *(const float4*)&W2[(size_t)(j + 1) * Dn + dd4];
            float4 w2 = *(const float4*)&W2[(size_t)(j + 2) * Dn + dd4];
            float4 w3 = *(const float4*)&W2[(size_t)(j + 3) * Dn + dd4];
            a.x += h4.x * w0.x + h4.y * w1.x + h4.z * w2.x + h4.w * w3.x;
            a.y += h4.x * w0.y + h4.y * w1.y + h4.z * w2.y + h4.w * w3.y;
            a.z += h4.x * w0.z + h4.y * w1.z + h4.z * w2.z + h4.w * w3.z;
            a.w += h4.x * w0.w + h4.y * w1.w + h4.z * w2.w + h4.w * w3.w;
        }
        *(float4*)&scratch[jh * 132 + dd4] = a;  // stride 132: 132%32=4 -> conflict-free combine
    }
    __syncthreads();
    if (tid < 128) {
        float e = b2[tid];
        #pragma unroll
        for (int p = 0; p < 16; ++p) e += scratch[p * 132 + tid];
        embs[tid] = e;
        out[4 * Kp + k * Dn + tid] = e;   // embedding output at offset 512
    }
    __syncthreads();

    // --- branch distances d1, d2 (waves 0-1) ---
    if (tid < 128) {
        float e  = embs[tid];
        float q1 = xs[tid] - e;        float v1 = q1 * q1;
        float q2 = xs[128 + tid] - e;  float v2 = q2 * q2;
        #pragma unroll
        for (int off = 32; off > 0; off >>= 1) {
            v1 += __shfl_down(v1, off);
            v2 += __shfl_down(v2, off);
        }
        if (lane == 0) { sD1[wid] = v1; sD2[wid] = v2; }
    }
    __syncthreads();

    // --- scalar epilogue (thread 0) ---
    if (tid == 0) {
        float s1 = sD1[0] + sD1[1];
        float s2 = sD2[0] + sD2[1];
        float d1 = sqrtf(s1 + 1e-12f);
        float d2 = sqrtf(s2 + 1e-12f);
        float rate1 = 1.0f / (d1 + 1e-4f);
        float rate2 = 1.0f / (d2 + 1e-4f);
        float branch1 = -(1.0f / rate1) * logf(u1[k]);
        float branch2 = -(1.0f / rate2) * logf(u2[k]);
        float lbp1 = logf(rate1) - rate1 * branch1;
        float lbp2 = logf(rate2) - rate2 * branch2;
        float lse  = logf(fS);                            // direct-sum logsumexp
        float lmp  = fW + 0.69314718055994531f - lse;     // + log(2)
        float lvp  = lmp + lbp1 + lbp2;
        int lc1 = leaf[k * Tn + i1];
        int lc2 = leaf[k * Tn + i2];
        int ones = sOnes - (lc1 == 1 ? 1 : 0) - (lc2 == 1 ? 1 : 0);
        float lvm = logf((float)(Nptr[0] - ones));

        out[k]                         = (float)i1;
        out[Kp + k]                    = (float)i2;
        out[2 * Kp + k]                = branch1;
        out[3 * Kp + k]                = branch2;
        out[4 * Kp + Kp * Dn + k]      = lvp;   // offset 16896
        out[4 * Kp + Kp * Dn + Kp + k] = lvm;   // offset 17024
    }
}

extern "C" void kernel_launch(void* const* d_in, const int* in_sizes, int n_in,
                              void* d_out, int out_size, void* d_ws, size_t ws_size,
                              hipStream_t stream) {
    const int*   Nptr = (const int*)  d_in[0];
    const int*   leaf = (const int*)  d_in[1];
    const float* emb  = (const float*)d_in[2];
    // d_in[3] log_felsensteins, d_in[4] site_positions: unused by reference
    const float* W1   = (const float*)d_in[5];
    const float* b1   = (const float*)d_in[6];
    const float* W2   = (const float*)d_in[7];
    const float* b2   = (const float*)d_in[8];
    const float* gum  = (const float*)d_in[9];
    const float* u1   = (const float*)d_in[10];
    const float* u2   = (const float*)d_in[11];
    float* out = (float*)d_out;

    ep_kernel<<<Kp, 512, 0, stream>>>(Nptr, leaf, emb, W1, b1, W2, b2, gum, u1, u2, out);
}

// Round 5
// 125.796 us; speedup vs baseline: 1.0714x; 1.0714x over previous
//
#include <hip/hip_runtime.h>
#include <math.h>

// Problem constants (match reference)
#define Kp 128
#define Tn 64
#define Dn 128
#define Hn 512
#define RS 136   // ushort row stride for bf16 E rows: 272 B (16B-aligned), +4 banks/row

typedef __attribute__((ext_vector_type(8))) short short8;   // 8 bf16 = 4 VGPRs (MFMA A/B frag)
typedef __attribute__((ext_vector_type(4))) float f32x4;    // MFMA C/D frag

__global__ __launch_bounds__(256, 1) void ep_kernel(
    const int*   __restrict__ Nptr,    // [1]
    const int*   __restrict__ leaf,    // K x 64 (int32)
    const float* __restrict__ emb,     // K x 64 x 128
    const float* __restrict__ W1,      // 256 x 512
    const float* __restrict__ b1,      // 512
    const float* __restrict__ W2,      // 512 x 128
    const float* __restrict__ b2,      // 128
    const float* __restrict__ gum,     // K x 4096
    const float* __restrict__ u1,      // K
    const float* __restrict__ u2,      // K
    float* __restrict__ out)           // 17152 floats
{
    const int k    = blockIdx.x;
    const int tid  = threadIdx.x;
    const int lane = tid & 63;
    const int wid  = tid >> 6;

    __shared__ unsigned short EH[Tn * RS];   // bf16 hi of embeddings, row-major, 17408 B
    __shared__ unsigned short EL[Tn * RS];   // bf16 lo residual, 17408 B
    __shared__ float xs[256];        // concat(child1, child2)
    __shared__ float hsh[Hn];        // hidden layer
    __shared__ float buf[1024];      // MLP partials
    __shared__ float nI[Tn];         // squared norms (diag of Gram)
    __shared__ float sBest[4]; __shared__ int sIdx[4]; __shared__ float sW[4];
    __shared__ float sSum[4];
    __shared__ float sD1[4]; __shared__ float sD2[4];
    __shared__ int   sOnes;
    __shared__ int   fIdx; __shared__ float fW;
    __shared__ float embs[Dn];

    // wave -> 2x2 block of 16x16 G-tiles: wid 0..3 -> (itp,jtp); covers all 4x4 tiles
    const int itp  = wid >> 1;       // tile-row pair
    const int jtp  = wid & 1;        // tile-col pair
    const int lrow = lane & 15;      // fragment row/col within tile
    const int lq   = lane >> 4;      // k-quad (A/B) & row-quad (C/D)

    // --- ones count (wave 0) ---
    if (tid < 64) {
        unsigned long long m = __ballot(leaf[k * Tn + tid] == 1);
        if (tid == 0) sOnes = __popcll(m);
    }

    // --- EARLY global loads: embeddings (8 f4) + this thread's 16 gumbel entries ---
    float4 ev[8];
    {
        const float4* src = (const float4*)(emb + (size_t)k * Tn * Dn);
        #pragma unroll
        for (int it = 0; it < 8; ++it) ev[it] = src[tid + it * 256];
    }
    float gv[16];
    {
        const float* gk = gum + (size_t)k * (Tn * Tn);
        #pragma unroll
        for (int a = 0; a < 2; ++a)
            #pragma unroll
            for (int b = 0; b < 2; ++b) {
                int it = 2 * itp + a, jt = 2 * jtp + b;
                int col = jt * 16 + lrow;
                #pragma unroll
                for (int r = 0; r < 4; ++r) {
                    int row = it * 16 + lq * 4 + r;
                    gv[(a * 2 + b) * 4 + r] = gk[row * Tn + col];
                }
            }
    }

    // --- pack split-bf16 embeddings into LDS (row-major; e = hi + lo, |err| <= 2^-16|e|) ---
    #pragma unroll
    for (int it = 0; it < 8; ++it) {
        int f4 = tid + it * 256;
        int i  = f4 >> 5;            // subtree row (32 f4 per 128-dim row)
        int d0 = (f4 & 31) << 2;     // starting dim
        float4 v = ev[it];
        unsigned int bx = __float_as_uint(v.x), by = __float_as_uint(v.y),
                     bz = __float_as_uint(v.z), bw = __float_as_uint(v.w);
        unsigned short hx = bx >> 16, hy = by >> 16, hz = bz >> 16, hw = bw >> 16;
        float rx = v.x - __uint_as_float((unsigned int)hx << 16);
        float ry = v.y - __uint_as_float((unsigned int)hy << 16);
        float rz = v.z - __uint_as_float((unsigned int)hz << 16);
        float rw = v.w - __uint_as_float((unsigned int)hw << 16);
        unsigned short lx = __float_as_uint(rx) >> 16, ly = __float_as_uint(ry) >> 16,
                       lz = __float_as_uint(rz) >> 16, lw = __float_as_uint(rw) >> 16;
        *(ushort4*)&EH[i * RS + d0] = make_ushort4(hx, hy, hz, hw);
        *(ushort4*)&EL[i * RS + d0] = make_ushort4(lx, ly, lz, lw);
    }
    __syncthreads();

    // --- MFMA Gram: G = Ehi.Ehi^T + Ehi.Elo^T + Elo.Ehi^T (fp32-accurate) ---
    // A-frag lane l: E[it*16 + (l&15)][k = lq*8 + j]; B-frag identical with jt row.
    // C/D: col = lane&15, row = lq*4 + reg. G symmetric -> orientation-safe.
    f32x4 acc[2][2] = {};
    const int ka = lq * 8;
    #pragma unroll
    for (int ks = 0; ks < 4; ++ks) {
        int kb  = ks * 32 + ka;
        int ra0 = ((2 * itp + 0) * 16 + lrow) * RS + kb;
        int ra1 = ra0 + 16 * RS;
        int rb0 = ((2 * jtp + 0) * 16 + lrow) * RS + kb;
        int rb1 = rb0 + 16 * RS;
        short8 ah0 = *(const short8*)&EH[ra0], ah1 = *(const short8*)&EH[ra1];
        short8 al0 = *(const short8*)&EL[ra0], al1 = *(const short8*)&EL[ra1];
        short8 bh0 = *(const short8*)&EH[rb0], bh1 = *(const short8*)&EH[rb1];
        short8 bl0 = *(const short8*)&EL[rb0], bl1 = *(const short8*)&EL[rb1];
        acc[0][0] = __builtin_amdgcn_mfma_f32_16x16x32_bf16(ah0, bh0, acc[0][0], 0, 0, 0);
        acc[0][1] = __builtin_amdgcn_mfma_f32_16x16x32_bf16(ah0, bh1, acc[0][1], 0, 0, 0);
        acc[1][0] = __builtin_amdgcn_mfma_f32_16x16x32_bf16(ah1, bh0, acc[1][0], 0, 0, 0);
        acc[1][1] = __builtin_amdgcn_mfma_f32_16x16x32_bf16(ah1, bh1, acc[1][1], 0, 0, 0);
        acc[0][0] = __builtin_amdgcn_mfma_f32_16x16x32_bf16(ah0, bl0, acc[0][0], 0, 0, 0);
        acc[0][1] = __builtin_amdgcn_mfma_f32_16x16x32_bf16(ah0, bl1, acc[0][1], 0, 0, 0);
        acc[1][0] = __builtin_amdgcn_mfma_f32_16x16x32_bf16(ah1, bl0, acc[1][0], 0, 0, 0);
        acc[1][1] = __builtin_amdgcn_mfma_f32_16x16x32_bf16(ah1, bl1, acc[1][1], 0, 0, 0);
        acc[0][0] = __builtin_amdgcn_mfma_f32_16x16x32_bf16(al0, bh0, acc[0][0], 0, 0, 0);
        acc[0][1] = __builtin_amdgcn_mfma_f32_16x16x32_bf16(al0, bh1, acc[0][1], 0, 0, 0);
        acc[1][0] = __builtin_amdgcn_mfma_f32_16x16x32_bf16(al1, bh0, acc[1][0], 0, 0, 0);
        acc[1][1] = __builtin_amdgcn_mfma_f32_16x16x32_bf16(al1, bh1, acc[1][1], 0, 0, 0);
    }

    // --- norms from diagonal tiles (waves 0 and 3 own (t,t) tiles) ---
    if (itp == jtp) {
        #pragma unroll
        for (int a = 0; a < 2; ++a) {
            if ((lrow >> 2) == lq) {               // one lane per diag column
                int c = lrow;
                int t = 2 * itp + a;
                f32x4 v = acc[a][a];
                int   s = c & 3;
                float val = (s == 0) ? v.x : (s == 1) ? v.y : (s == 2) ? v.z : v.w;
                nI[t * 16 + c] = val;
            }
        }
    }
    __syncthreads();   // nI visible to all

    // --- merge log-weights + argmax(w+g) + direct expsum ---
    float es = 0.0f, best = -INFINITY, bestW = 0.0f;
    int   bestIdx = 0;
    #pragma unroll
    for (int a = 0; a < 2; ++a)
        #pragma unroll
        for (int b = 0; b < 2; ++b) {
            int it = 2 * itp + a, jt = 2 * jtp + b;
            int col = jt * 16 + lrow;
            float njc = nI[col];
            f32x4 v = acc[a][b];
            float gvals[4] = {v.x, v.y, v.z, v.w};
            #pragma unroll
            for (int r = 0; r < 4; ++r) {
                int row = it * 16 + lq * 4 + r;
                float pd2 = nI[row] + njc - 2.0f * gvals[r];
                pd2 = fmaxf(pd2, 0.0f) + 1e-12f;
                float wv = (row == col) ? -INFINITY : -sqrtf(pd2);
                es += expf(wv);                    // expf(-inf)=0 handles diag
                float wg = wv + gv[(a * 2 + b) * 4 + r];
                int idx = row * Tn + col;
                if (wg > best || (wg == best && idx < bestIdx)) {
                    best = wg; bestIdx = idx; bestW = wv;
                }
            }
        }

    // --- single fused block reduction: argmax triple + expsum ---
    #pragma unroll
    for (int off = 32; off > 0; off >>= 1) {
        float ob = __shfl_down(best, off);
        int   oi = __shfl_down(bestIdx, off);
        float ow = __shfl_down(bestW, off);
        float oe = __shfl_down(es, off);
        if (ob > best || (ob == best && oi < bestIdx)) { best = ob; bestIdx = oi; bestW = ow; }
        es += oe;
    }
    if (lane == 0) { sBest[wid] = best; sIdx[wid] = bestIdx; sW[wid] = bestW; sSum[wid] = es; }
    __syncthreads();
    if (tid == 0) {
        best = sBest[0]; bestIdx = sIdx[0]; bestW = sW[0];
        #pragma unroll
        for (int q = 1; q < 4; ++q) {
            if (sBest[q] > best || (sBest[q] == best && sIdx[q] < bestIdx)) {
                best = sBest[q]; bestIdx = sIdx[q]; bestW = sW[q];
            }
        }
        fIdx = bestIdx; fW = bestW;
    }
    __syncthreads();

    const int i1 = fIdx >> 6;
    const int i2 = fIdx & 63;

    // --- gather children into xs = concat(c1, c2), reconstructed hi+lo ---
    {
        int d  = tid & 127;
        int ii = (tid < 128) ? i1 : i2;
        float hi = __uint_as_float((unsigned int)EH[ii * RS + d] << 16);
        float lo = __uint_as_float((unsigned int)EL[ii * RS + d] << 16);
        xs[tid] = hi + lo;
    }
    __syncthreads();

    // --- MLP layer 1: thread owns 4 cols (j0..j0+3) over one i-half; b128 loads ---
    {
        const int j0 = 4 * (tid & 127);
        const int ih = tid >> 7;
        const float* W1r = W1 + j0;
        float a0 = 0.0f, a1 = 0.0f, a2 = 0.0f, a3 = 0.0f;
        const int ibase = ih * 128;
        #pragma unroll 4
        for (int i = ibase; i < ibase + 128; i += 4) {
            float4 x  = *(const float4*)&xs[i];
            float4 w0 = *(const float4*)&W1r[(size_t)(i + 0) * Hn];
            float4 w1 = *(const float4*)&W1r[(size_t)(i + 1) * Hn];
            float4 w2 = *(const float4*)&W1r[(size_t)(i + 2) * Hn];
            float4 w3 = *(const float4*)&W1r[(size_t)(i + 3) * Hn];
            a0 += x.x * w0.x + x.y * w1.x + x.z * w2.x + x.w * w3.x;
            a1 += x.x * w0.y + x.y * w1.y + x.z * w2.y + x.w * w3.y;
            a2 += x.x * w0.z + x.y * w1.z + x.z * w2.z + x.w * w3.z;
            a3 += x.x * w0.w + x.y * w1.w + x.z * w2.w + x.w * w3.w;
        }
        *(float4*)&buf[ih * Hn + j0] = make_float4(a0, a1, a2, a3);
    }
    __syncthreads();
    // combine i-halves + bias + relu
    {
        int j = tid;
        hsh[j] = fmaxf(buf[j] + buf[Hn + j] + b1[j], 0.0f);
        j = tid + 256;
        hsh[j] = fmaxf(buf[j] + buf[Hn + j] + b1[j], 0.0f);
    }
    __syncthreads();

    // --- MLP layer 2: thread owns 4 dd-cols over a 64-wide j-slice (8-way split) ---
    {
        const int jh  = tid >> 5;          // 0..7
        const int dd4 = 4 * (tid & 31);    // 0..124
        float a0 = 0.0f, a1 = 0.0f, a2 = 0.0f, a3 = 0.0f;
        const int jbase = jh * 64;
        #pragma unroll 4
        for (int j = jbase; j < jbase + 64; j += 4) {
            float4 h4 = *(const float4*)&hsh[j];
            float4 w0 = *(const float4*)&W2[(size_t)(j + 0) * Dn + dd4];
            float4 w1 = *(const float4*)&W2[(size_t)(j + 1) * Dn + dd4];
            float4 w2 = *(const float4*)&W2[(size_t)(j + 2) * Dn + dd4];
            float4 w3 = *(const float4*)&W2[(size_t)(j + 3) * Dn + dd4];
            a0 += h4.x * w0.x + h4.y * w1.x + h4.z * w2.x + h4.w * w3.x;
            a1 += h4.x * w0.y + h4.y * w1.y + h4.z * w2.y + h4.w * w3.y;
            a2 += h4.x * w0.z + h4.y * w1.z + h4.z * w2.z + h4.w * w3.z;
            a3 += h4.x * w0.w + h4.y * w1.w + h4.z * w2.w + h4.w * w3.w;
        }
        *(float4*)&buf[jh * Dn + dd4] = make_float4(a0, a1, a2, a3);
    }
    __syncthreads();
    if (tid < 128) {
        float e = b2[tid];
        #pragma unroll
        for (int q = 0; q < 8; ++q) e += buf[q * Dn + tid];
        embs[tid] = e;
        out[4 * Kp + k * Dn + tid] = e;   // embedding output at offset 512
    }
    __syncthreads();

    // --- branch distances d1, d2 ---
    float v1 = 0.0f, v2 = 0.0f;
    if (tid < 128) {
        float e  = embs[tid];
        float q1 = xs[tid] - e;        v1 = q1 * q1;
        float q2 = xs[128 + tid] - e;  v2 = q2 * q2;
    }
    #pragma unroll
    for (int off = 32; off > 0; off >>= 1) {
        v1 += __shfl_down(v1, off);
        v2 += __shfl_down(v2, off);
    }
    if (lane == 0) { sD1[wid] = v1; sD2[wid] = v2; }
    __syncthreads();

    // --- scalar epilogue (thread 0) ---
    if (tid == 0) {
        float s1 = sD1[0] + sD1[1] + sD1[2] + sD1[3];
        float s2 = sD2[0] + sD2[1] + sD2[2] + sD2[3];
        float d1 = sqrtf(s1 + 1e-12f);
        float d2 = sqrtf(s2 + 1e-12f);
        float rate1 = 1.0f / (d1 + 1e-4f);
        float rate2 = 1.0f / (d2 + 1e-4f);
        float branch1 = -(1.0f / rate1) * logf(u1[k]);
        float branch2 = -(1.0f / rate2) * logf(u2[k]);
        float lbp1 = logf(rate1) - rate1 * branch1;
        float lbp2 = logf(rate2) - rate2 * branch2;
        float ssum = sSum[0] + sSum[1] + sSum[2] + sSum[3];
        float lse  = logf(ssum);                          // direct-sum logsumexp
        float lmp  = fW + 0.69314718055994531f - lse;     // + log(2)
        float lvp  = lmp + lbp1 + lbp2;
        int lc1 = leaf[k * Tn + i1];
        int lc2 = leaf[k * Tn + i2];
        int ones = sOnes - (lc1 == 1 ? 1 : 0) - (lc2 == 1 ? 1 : 0);
        float lvm = logf((float)(Nptr[0] - ones));

        out[k]                         = (float)i1;
        out[Kp + k]                    = (float)i2;
        out[2 * Kp + k]                = branch1;
        out[3 * Kp + k]                = branch2;
        out[4 * Kp + Kp * Dn + k]      = lvp;   // offset 16896
        out[4 * Kp + Kp * Dn + Kp + k] = lvm;   // offset 17024
    }
}

extern "C" void kernel_launch(void* const* d_in, const int* in_sizes, int n_in,
                              void* d_out, int out_size, void* d_ws, size_t ws_size,
                              hipStream_t stream) {
    const int*   Nptr = (const int*)  d_in[0];
    const int*   leaf = (const int*)  d_in[1];
    const float* emb  = (const float*)d_in[2];
    // d_in[3] log_felsensteins, d_in[4] site_positions: unused by reference
    const float* W1   = (const float*)d_in[5];
    const float* b1   = (const float*)d_in[6];
    const float* W2   = (const float*)d_in[7];
    const float* b2   = (const float*)d_in[8];
    const float* gum  = (const float*)d_in[9];
    const float* u1   = (const float*)d_in[10];
    const float* u2   = (const float*)d_in[11];
    float* out = (float*)d_out;

    ep_kernel<<<Kp, 256, 0, stream>>>(Nptr, leaf, emb, W1, b1, W2, b2, gum, u1, u2, out);
}